// Round 10
// baseline (9097.229 us; speedup 1.0000x reference)
//
// rev10: identical semantics to rev9; comment bumped to force fresh compile sha.
// Rounds 1-9: container ENOSPC at device compile/link; r4/r5/r9 show even the
// harness's own 19KB atexit write failing (Errno 28). Purely environment-side;
// needs /tmp cleanup or lease rotation. Resubmitting unchanged per methodology.
#include <hip/hip_runtime.h>
#include <math.h>

// ---- problem constants ----
constexpr int NB   = 2;     // batch
constexpr int NSG  = 2;     // ns slices
constexpr int NE   = 32;    // electrodes
constexpr int NT   = 40;    // time
constexpr int NF   = 37;    // input features
constexpr int DM   = 128;   // d_model
constexpr int NH   = 8;     // heads
constexpr int DH   = 16;    // head dim
constexpr int DF   = 512;   // dff
constexpr int NL   = 6;     // layers
constexpr int SEQL = NE * NT;            // 1280 keys per (b)
constexpr int NTOK = NB * NSG * NE * NT; // 5120 tokens
constexpr int NKV  = NB * SEQL;          // 2560 kv rows

constexpr float NEGBIG = -1e30f;

// ---------------- embed: h = x@Wf + bf + emb[e] ----------------
__global__ void k_embed(const float* __restrict__ x, const float* __restrict__ Wf,
                        const float* __restrict__ bf, const float* __restrict__ emb,
                        float* __restrict__ h) {
    int tok = blockIdx.x;
    int d = threadIdx.x;
    __shared__ float xs[NF];
    if (d < NF) xs[d] = x[tok * NF + d];
    __syncthreads();
    int e = (tok / NT) % NE;
    float acc = bf[d];
    for (int f = 0; f < NF; ++f) acc += xs[f] * Wf[f * DM + d];
    h[tok * DM + d] = acc + emb[e * DM + d];
}

// ---------------- layernorm (per token, 128 threads) ----------------
__global__ void k_ln(const float* __restrict__ h, const float* __restrict__ g,
                     const float* __restrict__ b, float* __restrict__ o) {
    int tok = blockIdx.x;
    int d = threadIdx.x;
    float v = h[tok * DM + d];
    int lane = d & 63, wave = d >> 6;
    __shared__ float s0[2], s1[2];
    float s = v;
    #pragma unroll
    for (int off = 32; off >= 1; off >>= 1) s += __shfl_xor(s, off);
    if (lane == 0) s0[wave] = s;
    __syncthreads();
    float mu = (s0[0] + s0[1]) * (1.0f / DM);
    float dv = v - mu;
    float sq = dv * dv;
    #pragma unroll
    for (int off = 32; off >= 1; off >>= 1) sq += __shfl_xor(sq, off);
    if (lane == 0) s1[wave] = sq;
    __syncthreads();
    float var = (s1[0] + s1[1]) * (1.0f / DM);
    o[tok * DM + d] = dv * rsqrtf(var + 1e-5f) * g[d] + b[d];
}

// ---------------- QKV projection + RoPE; 8 tokens/block ----------------
// All 8 tokens in a block share (b, ns, e) since NT=40 is divisible by 8.
__global__ void k_qkv(const float* __restrict__ h2,
                      const float* __restrict__ Wq, const float* __restrict__ bq,
                      const float* __restrict__ Wk, const float* __restrict__ bk,
                      const float* __restrict__ Wv, const float* __restrict__ bv,
                      float* __restrict__ qb, float* __restrict__ kb, float* __restrict__ vb) {
    int t0 = blockIdx.x * 8;
    int d = threadIdx.x;
    __shared__ float xs[8][DM], tq[8][DM], tk[8][DM];
    #pragma unroll
    for (int i = 0; i < 8; ++i) xs[i][d] = h2[(t0 + i) * DM + d];
    __syncthreads();
    float aq[8], ak[8], av[8];
    float bqv = bq[d], bkv = bk[d], bvv = bv[d];
    #pragma unroll
    for (int i = 0; i < 8; ++i) { aq[i] = bqv; ak[i] = bkv; av[i] = bvv; }
    for (int j = 0; j < DM; ++j) {
        float wq = Wq[j * DM + d], wk = Wk[j * DM + d], wv = Wv[j * DM + d];
        #pragma unroll
        for (int i = 0; i < 8; ++i) {
            float xv = xs[i][j];
            aq[i] += xv * wq; ak[i] += xv * wk; av[i] += xv * wv;
        }
    }
    #pragma unroll
    for (int i = 0; i < 8; ++i) { tq[i][d] = aq[i]; tk[i][d] = ak[i]; }
    __syncthreads();
    int hd = d & (DH - 1);
    int ns = (t0 / (NE * NT)) % NSG;   // block-uniform
    int b  = t0 / (NSG * NE * NT);
    for (int i = 0; i < 8; ++i) {
        int tok = t0 + i;
        int t = tok % NT;
        float qv, kv;
        if (hd < 8) {
            int ii = hd & 3;
            float freq = (ii == 0) ? 1.0f : (1.0f / 160.0f);
            float ang = (float)t * freq;
            float c = cosf(ang), s = sinf(ang);
            int base = d - hd;
            float xl = tq[i][base + ii], xr = tq[i][base + ii + 4];
            qv = (hd < 4) ? (xl * c + xr * s) : (xr * c - xl * s);
            float yl = tk[i][base + ii], yr = tk[i][base + ii + 4];
            kv = (hd < 4) ? (yl * c + yr * s) : (yr * c - yl * s);
        } else {
            qv = aq[i];
            kv = ak[i];
        }
        qb[tok * DM + d] = qv;
        if (ns == 0) {
            int et = tok % (NSG * NE * NT);  // = e*NT + t since ns==0
            int kvi = b * SEQL + et;
            kb[kvi * DM + d] = kv;
            vb[kvi * DM + d] = av[i];
        }
    }
}

// ---------------- attention: one wave per (query token, head) ----------------
// keys/values: slice ns=0 of the same batch, SEQL=1280 keys, 20 per lane.
__global__ void k_attn(const float* __restrict__ qb, const float* __restrict__ kb,
                       const float* __restrict__ vb, float* __restrict__ ab) {
    int tok = blockIdx.x;
    int head = blockIdx.y;
    int lane = threadIdx.x;
    int b  = tok / (NSG * NE * NT);
    int eq = (tok / NT) % NE;
    int tq_ = tok % NT;
    const float* qp = qb + tok * DM + head * DH;
    float qv[DH];
    #pragma unroll
    for (int i = 0; i < DH; ++i) qv[i] = qp[i];
    const float* kbase = kb + (size_t)b * SEQL * DM + head * DH;
    const float* vbase = vb + (size_t)b * SEQL * DM + head * DH;

    float s[20];
    float m = NEGBIG;
    for (int j = 0; j < 20; ++j) {
        int kk = lane + j * 64;
        int ek = kk / NT, tk_ = kk % NT;
        bool masked = (tk_ > tq_) || ((ek >= eq) && (tk_ == tq_));
        const float* kp = kbase + kk * DM;
        float dot = 0.0f;
        #pragma unroll
        for (int i = 0; i < DH; ++i) dot += qv[i] * kp[i];
        s[j] = masked ? NEGBIG : dot * 0.25f;   // HD^-0.5 = 0.25
        m = fmaxf(m, s[j]);
    }
    #pragma unroll
    for (int off = 32; off >= 1; off >>= 1) m = fmaxf(m, __shfl_xor(m, off));
    if (m < -1e29f) m = 0.0f;   // fully-masked row: ref sets m=0, all p -> 0

    float den = 0.0f;
    float acc[DH];
    #pragma unroll
    for (int i = 0; i < DH; ++i) acc[i] = 0.0f;
    for (int j = 0; j < 20; ++j) {
        int kk = lane + j * 64;
        // masked lanes: force exact 0
        float p = (s[j] <= NEGBIG) ? 0.0f : expf(s[j] - m);
        den += p;
        const float* vp = vbase + kk * DM;
        #pragma unroll
        for (int i = 0; i < DH; ++i) acc[i] += p * vp[i];
    }
    #pragma unroll
    for (int off = 32; off >= 1; off >>= 1) {
        den += __shfl_xor(den, off);
        #pragma unroll
        for (int i = 0; i < DH; ++i) acc[i] += __shfl_xor(acc[i], off);
    }
    float inv = 1.0f / ((den == 0.0f) ? 1.0f : den);
    if (lane < DH) ab[tok * DM + head * DH + lane] = acc[lane] * inv;
}

// ---------------- O-proj + residual; 8 tokens/block ----------------
__global__ void k_oproj(const float* __restrict__ a, const float* __restrict__ Wo,
                        const float* __restrict__ bo, float* __restrict__ h) {
    int t0 = blockIdx.x * 8;
    int d = threadIdx.x;
    __shared__ float xs[8][DM];
    #pragma unroll
    for (int i = 0; i < 8; ++i) xs[i][d] = a[(t0 + i) * DM + d];
    __syncthreads();
    float acc[8];
    float bv = bo[d];
    #pragma unroll
    for (int i = 0; i < 8; ++i) acc[i] = bv;
    for (int j = 0; j < DM; ++j) {
        float w = Wo[j * DM + d];
        #pragma unroll
        for (int i = 0; i < 8; ++i) acc[i] += xs[i][j] * w;
    }
    #pragma unroll
    for (int i = 0; i < 8; ++i) h[(t0 + i) * DM + d] += acc[i];
}

// ---------------- FF1 + exact GELU; 8 tokens/block, 512 threads ----------------
__global__ void k_ff1(const float* __restrict__ h2, const float* __restrict__ W1,
                      const float* __restrict__ b1, float* __restrict__ mid) {
    int t0 = blockIdx.x * 8;
    int d = threadIdx.x;  // 0..511
    __shared__ float xs[8 * DM];
    for (int idx = d; idx < 8 * DM; idx += DF) xs[idx] = h2[t0 * DM + idx];
    __syncthreads();
    float acc[8];
    float bv = b1[d];
    #pragma unroll
    for (int i = 0; i < 8; ++i) acc[i] = bv;
    for (int j = 0; j < DM; ++j) {
        float w = W1[j * DF + d];
        #pragma unroll
        for (int i = 0; i < 8; ++i) acc[i] += xs[i * DM + j] * w;
    }
    #pragma unroll
    for (int i = 0; i < 8; ++i) {
        float v = acc[i];
        float ge = 0.5f * v * (1.0f + erff(v * 0.70710678118654752f));
        mid[(t0 + i) * DF + d] = ge;
    }
}

// ---------------- FF2 + residual; 8 tokens/block, 128 threads ----------------
__global__ void k_ff2(const float* __restrict__ mid, const float* __restrict__ W2,
                      const float* __restrict__ b2, float* __restrict__ h) {
    int t0 = blockIdx.x * 8;
    int d = threadIdx.x;  // 0..127
    __shared__ float xs[8 * DF];
    for (int idx = d; idx < 8 * DF; idx += DM) xs[idx] = mid[t0 * DF + idx];
    __syncthreads();
    float acc[8];
    float bv = b2[d];
    #pragma unroll
    for (int i = 0; i < 8; ++i) acc[i] = bv;
    for (int j = 0; j < DF; ++j) {
        float w = W2[j * DM + d];
        #pragma unroll
        for (int i = 0; i < 8; ++i) acc[i] += xs[i * DF + j] * w;
    }
    #pragma unroll
    for (int i = 0; i < 8; ++i) h[(t0 + i) * DM + d] += acc[i];
}

// ---------------- final projection to scalar ----------------
__global__ void k_out(const float* __restrict__ h, const float* __restrict__ Wout,
                      const float* __restrict__ bout, float* __restrict__ out) {
    int tok = blockIdx.x;
    int d = threadIdx.x;
    float p = h[tok * DM + d] * Wout[d];
    #pragma unroll
    for (int off = 32; off >= 1; off >>= 1) p += __shfl_xor(p, off);
    __shared__ float ws_[2];
    if ((d & 63) == 0) ws_[d >> 6] = p;
    __syncthreads();
    if (d == 0) out[tok] = ws_[0] + ws_[1] + bout[0];
}

extern "C" void kernel_launch(void* const* d_in, const int* in_sizes, int n_in,
                              void* d_out, int out_size, void* d_ws, size_t ws_size,
                              hipStream_t stream) {
    const float* x    = (const float*)d_in[0];
    const float* emb  = (const float*)d_in[1];
    const float* Wf   = (const float*)d_in[2];
    const float* bf_  = (const float*)d_in[3];
    const float* Wq   = (const float*)d_in[4];
    const float* bq   = (const float*)d_in[5];
    const float* Wk   = (const float*)d_in[6];
    const float* bk   = (const float*)d_in[7];
    const float* Wv   = (const float*)d_in[8];
    const float* bv   = (const float*)d_in[9];
    const float* Wo   = (const float*)d_in[10];
    const float* bo   = (const float*)d_in[11];
    const float* W1   = (const float*)d_in[12];
    const float* b1   = (const float*)d_in[13];
    const float* W2   = (const float*)d_in[14];
    const float* b2   = (const float*)d_in[15];
    const float* g1   = (const float*)d_in[16];
    const float* be1  = (const float*)d_in[17];
    const float* g2   = (const float*)d_in[18];
    const float* be2  = (const float*)d_in[19];
    const float* Wout = (const float*)d_in[20];
    const float* bout = (const float*)d_in[21];

    float* ws = (float*)d_ws;
    float* h   = ws;                 // NTOK*DM
    float* h2  = h  + NTOK * DM;     // NTOK*DM
    float* qb  = h2 + NTOK * DM;     // NTOK*DM
    float* kb  = qb + NTOK * DM;     // NKV*DM
    float* vb  = kb + NKV * DM;      // NKV*DM
    float* ab  = vb + NKV * DM;      // NTOK*DM
    float* mid = ab + NTOK * DM;     // NTOK*DF

    k_embed<<<NTOK, DM, 0, stream>>>(x, Wf, bf_, emb, h);
    for (int l = 0; l < NL; ++l) {
        k_ln<<<NTOK, DM, 0, stream>>>(h, g1 + l * DM, be1 + l * DM, h2);
        k_qkv<<<NTOK / 8, DM, 0, stream>>>(h2,
            Wq + l * DM * DM, bq + l * DM,
            Wk + l * DM * DM, bk + l * DM,
            Wv + l * DM * DM, bv + l * DM,
            qb, kb, vb);
        dim3 ga(NTOK, NH);
        k_attn<<<ga, 64, 0, stream>>>(qb, kb, vb, ab);
        k_oproj<<<NTOK / 8, DM, 0, stream>>>(ab, Wo + l * DM * DM, bo + l * DM, h);
        k_ln<<<NTOK, DM, 0, stream>>>(h, g2 + l * DM, be2 + l * DM, h2);
        k_ff1<<<NTOK / 8, DF, 0, stream>>>(h2, W1 + l * DM * DF, b1 + l * DF, mid);
        k_ff2<<<NTOK / 8, DM, 0, stream>>>(mid, W2 + l * DF * DM, b2 + l * DM, h);
    }
    k_out<<<NTOK, DM, 0, stream>>>(h, Wout, bout, (float*)d_out);
}

// Round 12
// 1569.373 us; speedup vs baseline: 5.7967x; 5.7967x over previous
//
// rev12: identical semantics to rev11 (never ran - r11 ENOSPC at device link).
// r10 baseline measured: 9097us, absmax 2.4e-7, 44 dispatches.
// rev11/12 changes vs baseline:
// - K/V transposed + time-major => coalesced attn reads + causal-prefix early exit
// - online softmax, 8 heads/block (512 thr) in k_attn
// - LN1 fused into k_qkv, LN2 fused into k_ff1 (44 -> 32 dispatches)
#include <hip/hip_runtime.h>
#include <math.h>

constexpr int NB   = 2;
constexpr int NSG  = 2;
constexpr int NE   = 32;
constexpr int NT   = 40;
constexpr int NF   = 37;
constexpr int DM   = 128;
constexpr int NH   = 8;
constexpr int DH   = 16;
constexpr int DF   = 512;
constexpr int NL   = 6;
constexpr int SEQL = NE * NT;            // 1280 keys per batch
constexpr int NTOK = NB * NSG * NE * NT; // 5120 tokens

constexpr float NEGBIG = -1e30f;

// ---------------- embed: h = x@Wf + bf + emb[e] ----------------
__global__ void k_embed(const float* __restrict__ x, const float* __restrict__ Wf,
                        const float* __restrict__ bf, const float* __restrict__ emb,
                        float* __restrict__ h) {
    int tok = blockIdx.x;
    int d = threadIdx.x;
    __shared__ float xs[NF];
    if (d < NF) xs[d] = x[tok * NF + d];
    __syncthreads();
    int e = (tok / NT) % NE;
    float acc = bf[d];
    for (int f = 0; f < NF; ++f) acc += xs[f] * Wf[f * DM + d];
    h[tok * DM + d] = acc + emb[e * DM + d];
}

// ---------------- fused LN1 + QKV projection + RoPE; 8 tokens/block ----------------
// K/V written TRANSPOSED time-major: kt[((b*NH+h)*DH+dd)*SEQL + t*NE + e]
__global__ void k_qkv(const float* __restrict__ hin,
                      const float* __restrict__ g1, const float* __restrict__ be1,
                      const float* __restrict__ Wq, const float* __restrict__ bq,
                      const float* __restrict__ Wk, const float* __restrict__ bk,
                      const float* __restrict__ Wv, const float* __restrict__ bv,
                      float* __restrict__ qb, float* __restrict__ kt, float* __restrict__ vt) {
    int t0 = blockIdx.x * 8;
    int d = threadIdx.x;           // 0..127
    __shared__ float xs[8][DM], tq_[8][DM], tk_[8][DM];
    __shared__ float mus[8], rsd[8];
    #pragma unroll
    for (int i = 0; i < 8; ++i) xs[i][d] = hin[(t0 + i) * DM + d];
    __syncthreads();
    // LN stats: wave w handles tokens 4w..4w+3
    int w = d >> 6, lane = d & 63;
    for (int i = 4 * w; i < 4 * w + 4; ++i) {
        float a = xs[i][lane], b2 = xs[i][lane + 64];
        float s = a + b2;
        float sq = a * a + b2 * b2;
        #pragma unroll
        for (int off = 32; off >= 1; off >>= 1) {
            s  += __shfl_xor(s, off);
            sq += __shfl_xor(sq, off);
        }
        if (lane == 0) {
            float mu = s * (1.0f / DM);
            float var = sq * (1.0f / DM) - mu * mu;
            mus[i] = mu;
            rsd[i] = rsqrtf(var + 1e-5f);
        }
    }
    __syncthreads();
    float gd = g1[d], bd = be1[d];
    #pragma unroll
    for (int i = 0; i < 8; ++i) xs[i][d] = (xs[i][d] - mus[i]) * rsd[i] * gd + bd;
    __syncthreads();

    float aq[8], ak[8], av[8];
    float bqv = bq[d], bkv = bk[d], bvv = bv[d];
    #pragma unroll
    for (int i = 0; i < 8; ++i) { aq[i] = bqv; ak[i] = bkv; av[i] = bvv; }
    for (int j = 0; j < DM; ++j) {
        float wq = Wq[j * DM + d], wk = Wk[j * DM + d], wv = Wv[j * DM + d];
        #pragma unroll
        for (int i = 0; i < 8; ++i) {
            float xv = xs[i][j];
            aq[i] += xv * wq; ak[i] += xv * wk; av[i] += xv * wv;
        }
    }
    #pragma unroll
    for (int i = 0; i < 8; ++i) { tq_[i][d] = aq[i]; tk_[i][d] = ak[i]; }
    __syncthreads();
    int hd = d & (DH - 1);
    int ns = (t0 / (NE * NT)) % NSG;   // block-uniform
    int b  = t0 / (NSG * NE * NT);
    int e  = (t0 / NT) % NE;           // block-uniform
    int hrow = (b * NH + (d >> 4)) * DH + hd;   // transposed K/V row for this thread
    for (int i = 0; i < 8; ++i) {
        int tok = t0 + i;
        int t = tok % NT;
        float qv, kv;
        if (hd < 8) {
            int ii = hd & 3;
            float freq = (ii == 0) ? 1.0f : (1.0f / 160.0f);
            float ang = (float)t * freq;
            float c = cosf(ang), s = sinf(ang);
            float xl = tq_[i][d - hd + ii], xr = tq_[i][d - hd + ii + 4];
            qv = (hd < 4) ? (xl * c + xr * s) : (xr * c - xl * s);
            float yl = tk_[i][d - hd + ii], yr = tk_[i][d - hd + ii + 4];
            kv = (hd < 4) ? (yl * c + yr * s) : (yr * c - yl * s);
        } else {
            qv = aq[i];
            kv = ak[i];
        }
        qb[tok * DM + d] = qv;
        if (ns == 0) {
            int col = t * NE + e;      // time-major key index
            kt[hrow * SEQL + col] = kv;
            vt[hrow * SEQL + col] = av[i];
        }
    }
}

// ---------------- attention: one block per query token, wave w = head w ----------------
// time-major keys => mask is a causal PREFIX of length L = tq*NE + eq
__global__ void k_attn(const float* __restrict__ qb, const float* __restrict__ kt,
                       const float* __restrict__ vt, float* __restrict__ ab) {
    int tok = blockIdx.x;
    int head = threadIdx.x >> 6;
    int lane = threadIdx.x & 63;
    int b  = tok / (NSG * NE * NT);
    int eq = (tok / NT) % NE;
    int tq = tok % NT;
    int L = tq * NE + eq;              // allowed prefix length
    const float* qp = qb + tok * DM + head * DH;
    float qv[DH];
    #pragma unroll
    for (int i = 0; i < DH; ++i) qv[i] = qp[i];
    const float* ktp = kt + (size_t)(b * NH + head) * DH * SEQL;
    const float* vtp = vt + (size_t)(b * NH + head) * DH * SEQL;

    float m = NEGBIG, den = 0.0f;
    float acc[DH];
    #pragma unroll
    for (int i = 0; i < DH; ++i) acc[i] = 0.0f;
    int nj = (L + 63) >> 6;            // <= 20; nj*64-1 <= 1279 < SEQL (in-bounds)
    for (int j = 0; j < nj; ++j) {
        int kk = j * 64 + lane;
        float dot = 0.0f;
        #pragma unroll
        for (int i = 0; i < DH; ++i) dot += qv[i] * ktp[i * SEQL + kk];
        float s = dot * 0.25f;         // HD^-0.5
        if (kk < L) {
            float mn = fmaxf(m, s);
            float sf = expf(m - mn);   // 0 when m==NEGBIG, 1 when unchanged
            float p  = expf(s - mn);
            den = den * sf + p;
            #pragma unroll
            for (int i = 0; i < DH; ++i) acc[i] = acc[i] * sf + p * vtp[i * SEQL + kk];
            m = mn;
        }
    }
    // merge lanes: (m, den, acc)
    #pragma unroll
    for (int off = 32; off >= 1; off >>= 1) {
        float m2 = __shfl_xor(m, off);
        float d2 = __shfl_xor(den, off);
        float M = fmaxf(m, m2);
        float sf1 = expf(m - M), sf2 = expf(m2 - M);
        den = den * sf1 + d2 * sf2;
        #pragma unroll
        for (int i = 0; i < DH; ++i)
            acc[i] = acc[i] * sf1 + __shfl_xor(acc[i], off) * sf2;
        m = M;
    }
    float inv = 1.0f / ((den == 0.0f) ? 1.0f : den);  // fully-masked row -> exact 0
    if (lane < DH) ab[tok * DM + head * DH + lane] = acc[lane] * inv;
}

// ---------------- O-proj + residual; 8 tokens/block ----------------
__global__ void k_oproj(const float* __restrict__ a, const float* __restrict__ Wo,
                        const float* __restrict__ bo, float* __restrict__ h) {
    int t0 = blockIdx.x * 8;
    int d = threadIdx.x;
    __shared__ float xs[8][DM];
    #pragma unroll
    for (int i = 0; i < 8; ++i) xs[i][d] = a[(t0 + i) * DM + d];
    __syncthreads();
    float acc[8];
    float bv = bo[d];
    #pragma unroll
    for (int i = 0; i < 8; ++i) acc[i] = bv;
    for (int j = 0; j < DM; ++j) {
        float w = Wo[j * DM + d];
        #pragma unroll
        for (int i = 0; i < 8; ++i) acc[i] += xs[i][j] * w;
    }
    #pragma unroll
    for (int i = 0; i < 8; ++i) h[(t0 + i) * DM + d] += acc[i];
}

// ---------------- fused LN2 + FF1 + exact GELU; 8 tokens/block, 512 threads ----------------
__global__ void k_ff1(const float* __restrict__ hin,
                      const float* __restrict__ g2, const float* __restrict__ be2,
                      const float* __restrict__ W1, const float* __restrict__ b1,
                      float* __restrict__ mid) {
    int t0 = blockIdx.x * 8;
    int d = threadIdx.x;  // 0..511
    __shared__ float xs[8 * DM];
    __shared__ float mus[8], rsd[8];
    for (int idx = d; idx < 8 * DM; idx += DF) xs[idx] = hin[t0 * DM + idx];
    __syncthreads();
    // LN stats: wave w handles token w (8 waves)
    int w = d >> 6, lane = d & 63;
    {
        float a = xs[w * DM + lane], b2 = xs[w * DM + lane + 64];
        float s = a + b2;
        float sq = a * a + b2 * b2;
        #pragma unroll
        for (int off = 32; off >= 1; off >>= 1) {
            s  += __shfl_xor(s, off);
            sq += __shfl_xor(sq, off);
        }
        if (lane == 0) {
            float mu = s * (1.0f / DM);
            float var = sq * (1.0f / DM) - mu * mu;
            mus[w] = mu;
            rsd[w] = rsqrtf(var + 1e-5f);
        }
    }
    __syncthreads();
    for (int idx = d; idx < 8 * DM; idx += DF) {
        int i = idx >> 7, c = idx & 127;
        xs[idx] = (xs[idx] - mus[i]) * rsd[i] * g2[c] + be2[c];
    }
    __syncthreads();

    float acc[8];
    float bv = b1[d];
    #pragma unroll
    for (int i = 0; i < 8; ++i) acc[i] = bv;
    for (int j = 0; j < DM; ++j) {
        float w1 = W1[j * DF + d];
        #pragma unroll
        for (int i = 0; i < 8; ++i) acc[i] += xs[i * DM + j] * w1;
    }
    #pragma unroll
    for (int i = 0; i < 8; ++i) {
        float v = acc[i];
        mid[(t0 + i) * DF + d] = 0.5f * v * (1.0f + erff(v * 0.70710678118654752f));
    }
}

// ---------------- FF2 + residual; 8 tokens/block, 128 threads ----------------
__global__ void k_ff2(const float* __restrict__ mid, const float* __restrict__ W2,
                      const float* __restrict__ b2, float* __restrict__ h) {
    int t0 = blockIdx.x * 8;
    int d = threadIdx.x;
    __shared__ float xs[8 * DF];
    for (int idx = d; idx < 8 * DF; idx += DM) xs[idx] = mid[t0 * DF + idx];
    __syncthreads();
    float acc[8];
    float bv = b2[d];
    #pragma unroll
    for (int i = 0; i < 8; ++i) acc[i] = bv;
    for (int j = 0; j < DF; ++j) {
        float w = W2[j * DM + d];
        #pragma unroll
        for (int i = 0; i < 8; ++i) acc[i] += xs[i * DF + j] * w;
    }
    #pragma unroll
    for (int i = 0; i < 8; ++i) h[(t0 + i) * DM + d] += acc[i];
}

// ---------------- final projection to scalar ----------------
__global__ void k_out(const float* __restrict__ h, const float* __restrict__ Wout,
                      const float* __restrict__ bout, float* __restrict__ out) {
    int tok = blockIdx.x;
    int d = threadIdx.x;
    float p = h[tok * DM + d] * Wout[d];
    #pragma unroll
    for (int off = 32; off >= 1; off >>= 1) p += __shfl_xor(p, off);
    __shared__ float ws_[2];
    if ((d & 63) == 0) ws_[d >> 6] = p;
    __syncthreads();
    if (d == 0) out[tok] = ws_[0] + ws_[1] + bout[0];
}

extern "C" void kernel_launch(void* const* d_in, const int* in_sizes, int n_in,
                              void* d_out, int out_size, void* d_ws, size_t ws_size,
                              hipStream_t stream) {
    const float* x    = (const float*)d_in[0];
    const float* emb  = (const float*)d_in[1];
    const float* Wf   = (const float*)d_in[2];
    const float* bf_  = (const float*)d_in[3];
    const float* Wq   = (const float*)d_in[4];
    const float* bq   = (const float*)d_in[5];
    const float* Wk   = (const float*)d_in[6];
    const float* bk   = (const float*)d_in[7];
    const float* Wv   = (const float*)d_in[8];
    const float* bv   = (const float*)d_in[9];
    const float* Wo   = (const float*)d_in[10];
    const float* bo   = (const float*)d_in[11];
    const float* W1   = (const float*)d_in[12];
    const float* b1   = (const float*)d_in[13];
    const float* W2   = (const float*)d_in[14];
    const float* b2   = (const float*)d_in[15];
    const float* g1   = (const float*)d_in[16];
    const float* be1  = (const float*)d_in[17];
    const float* g2   = (const float*)d_in[18];
    const float* be2  = (const float*)d_in[19];
    const float* Wout = (const float*)d_in[20];
    const float* bout = (const float*)d_in[21];

    float* ws = (float*)d_ws;
    float* h   = ws;                         // NTOK*DM
    float* qb  = h  + NTOK * DM;             // NTOK*DM
    float* kt  = qb + NTOK * DM;             // NB*NH*DH*SEQL
    float* vt  = kt + NB * NH * DH * SEQL;   // NB*NH*DH*SEQL
    float* ab  = vt + NB * NH * DH * SEQL;   // NTOK*DM
    float* mid = ab + NTOK * DM;             // NTOK*DF

    k_embed<<<NTOK, DM, 0, stream>>>(x, Wf, bf_, emb, h);
    for (int l = 0; l < NL; ++l) {
        k_qkv<<<NTOK / 8, DM, 0, stream>>>(h,
            g1 + l * DM, be1 + l * DM,
            Wq + l * DM * DM, bq + l * DM,
            Wk + l * DM * DM, bk + l * DM,
            Wv + l * DM * DM, bv + l * DM,
            qb, kt, vt);
        k_attn<<<NTOK, 512, 0, stream>>>(qb, kt, vt, ab);
        k_oproj<<<NTOK / 8, DM, 0, stream>>>(ab, Wo + l * DM * DM, bo + l * DM, h);
        k_ff1<<<NTOK / 8, DF, 0, stream>>>(h, g2 + l * DM, be2 + l * DM,
                                           W1 + l * DM * DF, b1 + l * DF, mid);
        k_ff2<<<NTOK / 8, DM, 0, stream>>>(mid, W2 + l * DF * DM, b2 + l * DM, h);
    }
    k_out<<<NTOK, DM, 0, stream>>>(h, Wout, bout, (float*)d_out);
}